// Round 1
// baseline (581.329 us; speedup 1.0000x reference)
//
#include <hip/hip_runtime.h>
#include <hip/hip_fp16.h>

#define DIN 512
#define DHID 128
#define DOUT 4
#define BSH 8                 // bucket = 256 nodes
#define PA_CHUNK 8192         // edges per binning block (32/thread)
#define AST 72                // padded LDS row stride (fp16) for MFMA slabs

typedef _Float16 f16x8 __attribute__((ext_vector_type(8)));
typedef _Float16 f16x4 __attribute__((ext_vector_type(4)));
typedef float    f32x4 __attribute__((ext_vector_type(4)));

// ---------- edge dtype detection (int64 vs int32 ABI) ----------
__global__ void detect_i64_k(const int* __restrict__ raw, int* __restrict__ flag) {
  if (blockIdx.x == 0 && threadIdx.x == 0) {
    int z = 1;
    for (int k = 0; k < 8; ++k)
      if (raw[2 * k + 1] != 0) z = 0;
    flag[0] = z;
  }
}

// ---------- bucket histogram (391 buckets) via LDS ----------
__global__ __launch_bounds__(256) void bcount_k(const int* __restrict__ raw,
                                                const int* __restrict__ flag,
                                                int* __restrict__ gbcnt, int E) {
  __shared__ int h[512];
  const int tid = threadIdx.x;
  const int f = flag[0];
  for (int i = tid; i < 512; i += 256) h[i] = 0;
  __syncthreads();
  const size_t e0 = (size_t)blockIdx.x * PA_CHUNK;
  #pragma unroll
  for (int k = 0; k < 32; ++k) {
    size_t e = e0 + (size_t)k * 256 + tid;
    if (e < (size_t)E) {
      int d = f ? raw[2 * ((size_t)E + e)] : raw[(size_t)E + e];
      atomicAdd(&h[d >> BSH], 1);
    }
  }
  __syncthreads();
  for (int i = tid; i < 512; i += 256)
    if (h[i]) atomicAdd(&gbcnt[i], h[i]);
}

// ---------- bucket scan (single block) -> boffs, bcur; also offs[N]=E ----------
__global__ __launch_bounds__(512) void bscan_k(const int* __restrict__ gbcnt,
                                               int* __restrict__ boffs,
                                               int* __restrict__ bcur,
                                               int* __restrict__ offs,
                                               int nbkt, int N, int E) {
  __shared__ int sm[512];
  int t = threadIdx.x;
  int v = (t < nbkt) ? gbcnt[t] : 0;
  int x = v;
  sm[t] = x;
  __syncthreads();
  #pragma unroll
  for (int o = 1; o < 512; o <<= 1) {
    int y = (t >= o) ? sm[t - o] : 0;
    __syncthreads();
    x += y;
    sm[t] = x;
    __syncthreads();
  }
  if (t < nbkt) {
    boffs[t] = x - v;
    bcur[t] = x - v;
  }
  if (t == 0) {
    boffs[nbkt] = E;
    offs[N] = E;
  }
}

// ---------- binA: scatter packed (src<<8 | dst&255) into dst-bucket order ----
__global__ __launch_bounds__(256) void binA_k(const int* __restrict__ raw,
                                              const int* __restrict__ flag,
                                              int* __restrict__ bcur,
                                              unsigned* __restrict__ pairs, int E) {
  __shared__ int hist[512];
  __shared__ int base[512];
  const int tid = threadIdx.x;
  const int f = flag[0];
  const size_t e0 = (size_t)blockIdx.x * PA_CHUNK;
  for (int i = tid; i < 512; i += 256) hist[i] = 0;
  __syncthreads();
  int es[32], ed[32];
  #pragma unroll
  for (int k = 0; k < 32; ++k) {
    size_t e = e0 + (size_t)k * 256 + tid;
    if (e < (size_t)E) {
      es[k] = f ? raw[2 * e] : raw[e];
      ed[k] = f ? raw[2 * ((size_t)E + e)] : raw[(size_t)E + e];
      atomicAdd(&hist[ed[k] >> BSH], 1);
    } else {
      ed[k] = -1;
    }
  }
  __syncthreads();
  for (int i = tid; i < 512; i += 256) {
    int c = hist[i];
    base[i] = c ? atomicAdd(&bcur[i], c) : 0;
    hist[i] = 0;  // reuse as local cursor
  }
  __syncthreads();
  #pragma unroll
  for (int k = 0; k < 32; ++k) {
    if (ed[k] >= 0) {
      int b = ed[k] >> BSH;
      int pos = base[b] + atomicAdd(&hist[b], 1);
      pairs[pos] = ((unsigned)es[k] << 8) | ((unsigned)ed[k] & 255u);
    }
  }
}

// ---------- binB: per-bucket local count + scan -> offs/dis, then CSR fill ----
__global__ __launch_bounds__(256) void binB_k(const unsigned* __restrict__ pairs,
                                              const int* __restrict__ boffs,
                                              int* __restrict__ csr,
                                              int* __restrict__ offs,
                                              float* __restrict__ dis, int N) {
  __shared__ int lcnt[256];
  __shared__ int sc[256];
  const int tid = threadIdx.x;
  const int n0 = blockIdx.x << BSH;
  const int lo = boffs[blockIdx.x];
  const int hi = boffs[blockIdx.x + 1];
  lcnt[tid] = 0;
  __syncthreads();
  for (int j = lo + tid; j < hi; j += 256) atomicAdd(&lcnt[(int)(pairs[j] & 255u)], 1);
  __syncthreads();
  int v = lcnt[tid];
  int x = v;
  sc[tid] = x;
  __syncthreads();
  #pragma unroll
  for (int o = 1; o < 256; o <<= 1) {
    int y = (tid >= o) ? sc[tid - o] : 0;
    __syncthreads();
    x += y;
    sc[tid] = x;
    __syncthreads();
  }
  const int base = lo + x - v;   // node's CSR start
  const int node = n0 + tid;
  if (node < N) {
    offs[node] = base;
    dis[node] = rsqrtf((float)v + 1.0f);   // deg = in-degree + self-loop
  }
  __syncthreads();
  lcnt[tid] = base;   // reuse as cursor
  __syncthreads();
  for (int j = lo + tid; j < hi; j += 256) {
    unsigned p = pairs[j];
    int dl = (int)(p & 255u);
    int pos = atomicAdd(&lcnt[dl], 1);
    csr[pos] = (int)(p >> 8);   // lands in this bucket's span -> L2 absorbs
  }
}

// ---------- W1 split to fp16 hi/lo, transposed [128][512] ----------
__global__ __launch_bounds__(256) void wsplit_k(const float* __restrict__ W1,
                                                __half* __restrict__ Wth,
                                                __half* __restrict__ Wtl) {
  int idx = blockIdx.x * 256 + threadIdx.x;   // 0..65535
  if (idx >= DIN * DHID) return;
  int k = idx >> 7;    // 0..511
  int n = idx & 127;
  float w = W1[idx];   // W1[k][n], coalesced read
  _Float16 hi = (_Float16)w;
  _Float16 lo = (_Float16)(w - (float)hi);
  Wth[(size_t)n * DIN + k] = *(__half*)&hi;
  Wtl[(size_t)n * DIN + k] = *(__half*)&lo;
}

// ---------- GEMM1 via split-fp16 MFMA: hs = fp16((X@W1) * dis) ----------
// Software-pipelined: register prefetch of next K-tile (issue-early /
// LDS-write-late, T14) hides global-load latency under the MFMA phase.
__global__ __launch_bounds__(256, 2) void gemm1_k(const float* __restrict__ A,
                                                  const __half* __restrict__ Bth,
                                                  const __half* __restrict__ Btl,
                                                  const float* __restrict__ dis,
                                                  __half* __restrict__ hs, int N) {
  __shared__ _Float16 smem[4 * 128 * AST];   // Ah | Al | Bh | Bl = 73728 B
  __shared__ float sdis[128];
  _Float16* sAh = smem;
  _Float16* sAl = smem + 128 * AST;
  _Float16* sBh = smem + 2 * 128 * AST;
  _Float16* sBl = smem + 3 * 128 * AST;
  const int tid = threadIdx.x;
  const int wave = tid >> 6, lane = tid & 63;
  const int lr = lane & 15, quad = lane >> 4;
  const int m0 = blockIdx.x * 128;
  const int mbase = (wave >> 1) * 64;   // wave owns 64x64 of the 128x128 tile
  const int nbase = (wave & 1) * 64;
  if (tid < 128) sdis[tid] = (m0 + tid < N) ? dis[m0 + tid] : 0.f;

  f32x4 acc[4][4];
  #pragma unroll
  for (int mt = 0; mt < 4; ++mt)
    #pragma unroll
    for (int nt = 0; nt < 4; ++nt) acc[mt][nt] = (f32x4){0.f, 0.f, 0.f, 0.f};

  // prefetch registers: next K-tile of A (fp32) and B (fp16 hi/lo)
  float4 pa[8];
  uint4  pbh[4], pbl[4];

  auto issue_tile = [&](int k0) {
    #pragma unroll
    for (int l = 0; l < 8; ++l) {
      int idx = l * 256 + tid;
      int row = idx >> 4;
      int kk = (idx & 15) << 2;
      int gr = m0 + row;
      pa[l] = (gr < N) ? *(const float4*)(A + (size_t)gr * DIN + k0 + kk)
                       : make_float4(0.f, 0.f, 0.f, 0.f);
    }
    #pragma unroll
    for (int l = 0; l < 4; ++l) {
      int idx = l * 256 + tid;
      int row = idx >> 3;
      int kk = (idx & 7) << 3;
      pbh[l] = *(const uint4*)(Bth + (size_t)row * DIN + k0 + kk);
      pbl[l] = *(const uint4*)(Btl + (size_t)row * DIN + k0 + kk);
    }
  };

  auto write_lds = [&]() {
    #pragma unroll
    for (int l = 0; l < 8; ++l) {
      int idx = l * 256 + tid;
      int row = idx >> 4;
      int kk = (idx & 15) << 2;
      float4 v = pa[l];
      _Float16 h0 = (_Float16)v.x, h1 = (_Float16)v.y,
               h2 = (_Float16)v.z, h3 = (_Float16)v.w;
      f16x4 hi4 = {h0, h1, h2, h3};
      f16x4 lo4 = {(_Float16)(v.x - (float)h0), (_Float16)(v.y - (float)h1),
                   (_Float16)(v.z - (float)h2), (_Float16)(v.w - (float)h3)};
      *(f16x4*)&sAh[row * AST + kk] = hi4;
      *(f16x4*)&sAl[row * AST + kk] = lo4;
    }
    #pragma unroll
    for (int l = 0; l < 4; ++l) {
      int idx = l * 256 + tid;
      int row = idx >> 3;
      int kk = (idx & 7) << 3;
      *(uint4*)&sBh[row * AST + kk] = pbh[l];
      *(uint4*)&sBl[row * AST + kk] = pbl[l];
    }
  };

  issue_tile(0);   // prologue: tile 0 in flight

  for (int k0 = 0; k0 < DIN; k0 += 64) {
    write_lds();         // consume regs for tile k0 (waits vmcnt here only)
    __syncthreads();
    if (k0 + 64 < DIN) issue_tile(k0 + 64);   // next tile overlaps MFMA below
    #pragma unroll
    for (int ks = 0; ks < 2; ++ks) {
      const int ko = ks * 32 + quad * 8;
      f16x8 ah[4], al[4];
      #pragma unroll
      for (int mt = 0; mt < 4; ++mt) {
        int r = mbase + mt * 16 + lr;
        ah[mt] = *(const f16x8*)&sAh[r * AST + ko];
        al[mt] = *(const f16x8*)&sAl[r * AST + ko];
      }
      #pragma unroll
      for (int nt = 0; nt < 4; ++nt) {
        int c = nbase + nt * 16 + lr;
        f16x8 bh = *(const f16x8*)&sBh[c * AST + ko];
        f16x8 bl = *(const f16x8*)&sBl[c * AST + ko];
        #pragma unroll
        for (int mt = 0; mt < 4; ++mt) {
          acc[mt][nt] = __builtin_amdgcn_mfma_f32_16x16x32_f16(al[mt], bh, acc[mt][nt], 0, 0, 0);
          acc[mt][nt] = __builtin_amdgcn_mfma_f32_16x16x32_f16(ah[mt], bl, acc[mt][nt], 0, 0, 0);
          acc[mt][nt] = __builtin_amdgcn_mfma_f32_16x16x32_f16(ah[mt], bh, acc[mt][nt], 0, 0, 0);
        }
      }
    }
    __syncthreads();
  }
  // epilogue: scale by dis, round to fp16 in LDS [128][136], coalesced store
  #pragma unroll
  for (int mt = 0; mt < 4; ++mt) {
    #pragma unroll
    for (int nt = 0; nt < 4; ++nt) {
      int col = nbase + nt * 16 + lr;
      #pragma unroll
      for (int r = 0; r < 4; ++r) {
        int row = mbase + mt * 16 + quad * 4 + r;
        smem[row * 136 + col] = (_Float16)(acc[mt][nt][r] * sdis[row]);
      }
    }
  }
  __syncthreads();
  #pragma unroll
  for (int l = 0; l < 8; ++l) {
    int idx = l * 256 + tid;
    int row = idx >> 4;
    int c = (idx & 15) << 3;
    int gr = m0 + row;
    if (gr < N)
      *(uint4*)(hs + (size_t)gr * DHID + c) = *(uint4*)&smem[row * 136 + c];
  }
}

// ---------- fused agg1, unroll-8 gather for memory-level parallelism ----------
__global__ __launch_bounds__(256) void agg1_k(const __half* __restrict__ hs,
                                              const float* __restrict__ dis,
                                              const int* __restrict__ offs,
                                              const int* __restrict__ csr,
                                              const float* __restrict__ W2,
                                              const float* __restrict__ b1,
                                              float* __restrict__ gs, int N) {
  const int wid = threadIdx.x >> 6;
  const int lane = threadIdx.x & 63;
  const int i = blockIdx.x * 4 + wid;
  if (i >= N) return;
  const int f = lane * 2;
  const __half* hp = hs + f;   // lane-fixed column base
  float ax = 0.f, ay = 0.f;
  const int beg = offs[i], end = offs[i + 1];
  for (int base = beg; base < end; base += 64) {
    int sj = 0;
    if (base + lane < end) sj = csr[base + lane];  // coalesced edge-id load
    const int n = min(64, end - base);
    int t = 0;
    for (; t + 8 <= n; t += 8) {   // 8 independent gathers in flight
      int s0 = __shfl(sj, t + 0, 64), s1 = __shfl(sj, t + 1, 64);
      int s2 = __shfl(sj, t + 2, 64), s3 = __shfl(sj, t + 3, 64);
      int s4 = __shfl(sj, t + 4, 64), s5 = __shfl(sj, t + 5, 64);
      int s6 = __shfl(sj, t + 6, 64), s7 = __shfl(sj, t + 7, 64);
      __half2 h0 = *(const __half2*)(hp + (size_t)s0 * DHID);
      __half2 h1 = *(const __half2*)(hp + (size_t)s1 * DHID);
      __half2 h2 = *(const __half2*)(hp + (size_t)s2 * DHID);
      __half2 h3 = *(const __half2*)(hp + (size_t)s3 * DHID);
      __half2 h4 = *(const __half2*)(hp + (size_t)s4 * DHID);
      __half2 h5 = *(const __half2*)(hp + (size_t)s5 * DHID);
      __half2 h6 = *(const __half2*)(hp + (size_t)s6 * DHID);
      __half2 h7 = *(const __half2*)(hp + (size_t)s7 * DHID);
      float2 f0 = __half22float2(h0), f1 = __half22float2(h1);
      float2 f2 = __half22float2(h2), f3 = __half22float2(h3);
      float2 f4 = __half22float2(h4), f5 = __half22float2(h5);
      float2 f6 = __half22float2(h6), f7 = __half22float2(h7);
      ax += ((f0.x + f1.x) + (f2.x + f3.x)) + ((f4.x + f5.x) + (f6.x + f7.x));
      ay += ((f0.y + f1.y) + (f2.y + f3.y)) + ((f4.y + f5.y) + (f6.y + f7.y));
    }
    for (; t < n; ++t) {
      int s = __shfl(sj, t, 64);
      float2 hf = __half22float2(*(const __half2*)(hp + (size_t)s * DHID));
      ax += hf.x;
      ay += hf.y;
    }
  }
  {  // self-loop
    float2 hf = __half22float2(*(const __half2*)(hp + (size_t)i * DHID));
    ax += hf.x;
    ay += hf.y;
  }
  const float di = dis[i];
  float v0 = fmaxf(fmaf(ax, di, b1[f]), 0.f);
  float v1 = fmaxf(fmaf(ay, di, b1[f + 1]), 0.f);
  float p0 = fmaf(v0, W2[f * 4 + 0], v1 * W2[f * 4 + 4]);
  float p1 = fmaf(v0, W2[f * 4 + 1], v1 * W2[f * 4 + 5]);
  float p2 = fmaf(v0, W2[f * 4 + 2], v1 * W2[f * 4 + 6]);
  float p3 = fmaf(v0, W2[f * 4 + 3], v1 * W2[f * 4 + 7]);
  #pragma unroll
  for (int o = 32; o > 0; o >>= 1) {
    p0 += __shfl_xor(p0, o, 64);
    p1 += __shfl_xor(p1, o, 64);
    p2 += __shfl_xor(p2, o, 64);
    p3 += __shfl_xor(p3, o, 64);
  }
  if (lane == 0)
    *(float4*)(gs + (size_t)i * DOUT) = make_float4(p0 * di, p1 * di, p2 * di, p3 * di);
}

// ---------- layer-2: out = dis_i*(sum gs[s] + gs[i]) + b2, unroll-4 ----------
__global__ __launch_bounds__(256) void agg2_k(const float* __restrict__ gs,
                                              const float* __restrict__ dis,
                                              const int* __restrict__ offs,
                                              const int* __restrict__ csr,
                                              const float* __restrict__ b2,
                                              float* __restrict__ out, int N) {
  int i = blockIdx.x * 256 + threadIdx.x;
  if (i >= N) return;
  float a0 = 0.f, a1 = 0.f, a2 = 0.f, a3 = 0.f;
  const int beg = offs[i], end = offs[i + 1];
  int j = beg;
  for (; j + 4 <= end; j += 4) {
    int s0 = csr[j], s1 = csr[j + 1], s2 = csr[j + 2], s3 = csr[j + 3];
    float4 g0 = *(const float4*)(gs + (size_t)s0 * DOUT);
    float4 g1 = *(const float4*)(gs + (size_t)s1 * DOUT);
    float4 g2 = *(const float4*)(gs + (size_t)s2 * DOUT);
    float4 g3 = *(const float4*)(gs + (size_t)s3 * DOUT);
    a0 += (g0.x + g1.x) + (g2.x + g3.x);
    a1 += (g0.y + g1.y) + (g2.y + g3.y);
    a2 += (g0.z + g1.z) + (g2.z + g3.z);
    a3 += (g0.w + g1.w) + (g2.w + g3.w);
  }
  for (; j < end; ++j) {
    int s = csr[j];
    float4 gv = *(const float4*)(gs + (size_t)s * DOUT);
    a0 += gv.x; a1 += gv.y; a2 += gv.z; a3 += gv.w;
  }
  const float di = dis[i];
  float4 gi = *(const float4*)(gs + (size_t)i * DOUT);
  float4 o4;
  o4.x = fmaf(a0 + gi.x, di, b2[0]);
  o4.y = fmaf(a1 + gi.y, di, b2[1]);
  o4.z = fmaf(a2 + gi.z, di, b2[2]);
  o4.w = fmaf(a3 + gi.w, di, b2[3]);
  *(float4*)(out + (size_t)i * DOUT) = o4;
}

extern "C" void kernel_launch(void* const* d_in, const int* in_sizes, int n_in,
                              void* d_out, int out_size, void* d_ws, size_t ws_size,
                              hipStream_t stream) {
  const float* x  = (const float*)d_in[0];
  const int*   raw = (const int*)d_in[1];
  const float* W1 = (const float*)d_in[2];
  const float* b1 = (const float*)d_in[3];
  const float* W2 = (const float*)d_in[4];
  const float* b2 = (const float*)d_in[5];
  float* out = (float*)d_out;

  const int N = in_sizes[0] / DIN;   // 100000
  const int E = in_sizes[1] / 2;     // 3200000

  char* ws = (char*)d_ws;
  size_t off = 0;
  auto carve = [&](size_t bytes) -> char* {
    char* p = ws + off;
    off = (off + bytes + 255) & ~(size_t)255;
    return p;
  };
  float*    dis  = (float*)carve((size_t)N * 4);
  int*      offs = (int*)carve((size_t)(N + 1) * 4);
  int*      csr  = (int*)carve((size_t)E * 4);
  unsigned* pairs= (unsigned*)carve((size_t)E * 4);
  int*      boffs= (int*)carve(513 * 4);
  int*      bcur = (int*)carve(512 * 4);
  int*      gbcnt= (int*)carve(512 * 4);
  int*      flag = (int*)carve(256);
  __half*   Wth  = (__half*)carve((size_t)DIN * DHID * 2);
  __half*   Wtl  = (__half*)carve((size_t)DIN * DHID * 2);
  __half*   hs   = (__half*)carve((size_t)N * DHID * 2);
  float*    gs   = (float*)carve((size_t)N * DOUT * 4);
  (void)ws_size; (void)n_in; (void)out_size;

  const int gN = (N + 255) / 256;
  const int nbkt = (N + (1 << BSH) - 1) >> BSH;   // 391
  const int gA = (E + PA_CHUNK - 1) / PA_CHUNK;   // 391

  detect_i64_k<<<1, 64, 0, stream>>>(raw, flag);
  hipMemsetAsync(gbcnt, 0, 512 * 4, stream);
  bcount_k<<<gA, 256, 0, stream>>>(raw, flag, gbcnt, E);
  bscan_k<<<1, 512, 0, stream>>>(gbcnt, boffs, bcur, offs, nbkt, N, E);
  binA_k<<<gA, 256, 0, stream>>>(raw, flag, bcur, pairs, E);
  binB_k<<<nbkt, 256, 0, stream>>>(pairs, boffs, csr, offs, dis, N);
  wsplit_k<<<(DIN * DHID + 255) / 256, 256, 0, stream>>>(W1, Wth, Wtl);
  gemm1_k<<<(N + 127) / 128, 256, 0, stream>>>(x, Wth, Wtl, dis, hs, N);
  agg1_k<<<(N + 3) / 4, 256, 0, stream>>>(hs, dis, offs, csr, W2, b1, gs, N);
  agg2_k<<<gN, 256, 0, stream>>>(gs, dis, offs, csr, b2, out, N);
}

// Round 2
// 555.213 us; speedup vs baseline: 1.0470x; 1.0470x over previous
//
#include <hip/hip_runtime.h>
#include <hip/hip_fp16.h>

#define DIN 512
#define DHID 128
#define DOUT 4
#define BSH 8                 // bucket = 256 nodes
#define PA_CHUNK 8192         // edges per binning block (32/thread)
#define BST 40                // padded LDS row stride (fp16) for k32 MFMA slabs

typedef _Float16 f16x8 __attribute__((ext_vector_type(8)));
typedef _Float16 f16x4 __attribute__((ext_vector_type(4)));
typedef float    f32x4 __attribute__((ext_vector_type(4)));

// ---------- edge dtype detection (int64 vs int32 ABI) ----------
__global__ void detect_i64_k(const int* __restrict__ raw, int* __restrict__ flag) {
  if (blockIdx.x == 0 && threadIdx.x == 0) {
    int z = 1;
    for (int k = 0; k < 8; ++k)
      if (raw[2 * k + 1] != 0) z = 0;
    flag[0] = z;
  }
}

// ---------- bucket histogram (391 buckets) via LDS ----------
__global__ __launch_bounds__(256) void bcount_k(const int* __restrict__ raw,
                                                const int* __restrict__ flag,
                                                int* __restrict__ gbcnt, int E) {
  __shared__ int h[512];
  const int tid = threadIdx.x;
  const int f = flag[0];
  for (int i = tid; i < 512; i += 256) h[i] = 0;
  __syncthreads();
  const size_t e0 = (size_t)blockIdx.x * PA_CHUNK;
  #pragma unroll
  for (int k = 0; k < 32; ++k) {
    size_t e = e0 + (size_t)k * 256 + tid;
    if (e < (size_t)E) {
      int d = f ? raw[2 * ((size_t)E + e)] : raw[(size_t)E + e];
      atomicAdd(&h[d >> BSH], 1);
    }
  }
  __syncthreads();
  for (int i = tid; i < 512; i += 256)
    if (h[i]) atomicAdd(&gbcnt[i], h[i]);
}

// ---------- bucket scan (single block) -> boffs, bcur; also offs[N]=E ----------
__global__ __launch_bounds__(512) void bscan_k(const int* __restrict__ gbcnt,
                                               int* __restrict__ boffs,
                                               int* __restrict__ bcur,
                                               int* __restrict__ offs,
                                               int nbkt, int N, int E) {
  __shared__ int sm[512];
  int t = threadIdx.x;
  int v = (t < nbkt) ? gbcnt[t] : 0;
  int x = v;
  sm[t] = x;
  __syncthreads();
  #pragma unroll
  for (int o = 1; o < 512; o <<= 1) {
    int y = (t >= o) ? sm[t - o] : 0;
    __syncthreads();
    x += y;
    sm[t] = x;
    __syncthreads();
  }
  if (t < nbkt) {
    boffs[t] = x - v;
    bcur[t] = x - v;
  }
  if (t == 0) {
    boffs[nbkt] = E;
    offs[N] = E;
  }
}

// ---------- binA: scatter packed (src<<8 | dst&255) into dst-bucket order ----
__global__ __launch_bounds__(256) void binA_k(const int* __restrict__ raw,
                                              const int* __restrict__ flag,
                                              int* __restrict__ bcur,
                                              unsigned* __restrict__ pairs, int E) {
  __shared__ int hist[512];
  __shared__ int base[512];
  const int tid = threadIdx.x;
  const int f = flag[0];
  const size_t e0 = (size_t)blockIdx.x * PA_CHUNK;
  for (int i = tid; i < 512; i += 256) hist[i] = 0;
  __syncthreads();
  int es[32], ed[32];
  #pragma unroll
  for (int k = 0; k < 32; ++k) {
    size_t e = e0 + (size_t)k * 256 + tid;
    if (e < (size_t)E) {
      es[k] = f ? raw[2 * e] : raw[e];
      ed[k] = f ? raw[2 * ((size_t)E + e)] : raw[(size_t)E + e];
      atomicAdd(&hist[ed[k] >> BSH], 1);
    } else {
      ed[k] = -1;
    }
  }
  __syncthreads();
  for (int i = tid; i < 512; i += 256) {
    int c = hist[i];
    base[i] = c ? atomicAdd(&bcur[i], c) : 0;
    hist[i] = 0;  // reuse as local cursor
  }
  __syncthreads();
  #pragma unroll
  for (int k = 0; k < 32; ++k) {
    if (ed[k] >= 0) {
      int b = ed[k] >> BSH;
      int pos = base[b] + atomicAdd(&hist[b], 1);
      pairs[pos] = ((unsigned)es[k] << 8) | ((unsigned)ed[k] & 255u);
    }
  }
}

// ---------- binB: per-bucket local count + scan -> offs/dis, then CSR fill ----
__global__ __launch_bounds__(256) void binB_k(const unsigned* __restrict__ pairs,
                                              const int* __restrict__ boffs,
                                              int* __restrict__ csr,
                                              int* __restrict__ offs,
                                              float* __restrict__ dis, int N) {
  __shared__ int lcnt[256];
  __shared__ int sc[256];
  const int tid = threadIdx.x;
  const int n0 = blockIdx.x << BSH;
  const int lo = boffs[blockIdx.x];
  const int hi = boffs[blockIdx.x + 1];
  lcnt[tid] = 0;
  __syncthreads();
  for (int j = lo + tid; j < hi; j += 256) atomicAdd(&lcnt[(int)(pairs[j] & 255u)], 1);
  __syncthreads();
  int v = lcnt[tid];
  int x = v;
  sc[tid] = x;
  __syncthreads();
  #pragma unroll
  for (int o = 1; o < 256; o <<= 1) {
    int y = (tid >= o) ? sc[tid - o] : 0;
    __syncthreads();
    x += y;
    sc[tid] = x;
    __syncthreads();
  }
  const int base = lo + x - v;   // node's CSR start
  const int node = n0 + tid;
  if (node < N) {
    offs[node] = base;
    dis[node] = rsqrtf((float)v + 1.0f);   // deg = in-degree + self-loop
  }
  __syncthreads();
  lcnt[tid] = base;   // reuse as cursor
  __syncthreads();
  for (int j = lo + tid; j < hi; j += 256) {
    unsigned p = pairs[j];
    int dl = (int)(p & 255u);
    int pos = atomicAdd(&lcnt[dl], 1);
    csr[pos] = (int)(p >> 8);   // lands in this bucket's span -> L2 absorbs
  }
}

// ---------- W1 split to fp16 hi/lo, transposed [128][512] ----------
__global__ __launch_bounds__(256) void wsplit_k(const float* __restrict__ W1,
                                                __half* __restrict__ Wth,
                                                __half* __restrict__ Wtl) {
  int idx = blockIdx.x * 256 + threadIdx.x;   // 0..65535
  if (idx >= DIN * DHID) return;
  int k = idx >> 7;    // 0..511
  int n = idx & 127;
  float w = W1[idx];   // W1[k][n], coalesced read
  _Float16 hi = (_Float16)w;
  _Float16 lo = (_Float16)(w - (float)hi);
  Wth[(size_t)n * DIN + k] = *(__half*)&hi;
  Wtl[(size_t)n * DIN + k] = *(__half*)&lo;
}

// ---------- GEMM1 via split-fp16 MFMA: hs = fp16((X@W1) * dis) ----------
// K-step 32 (LDS 40960B -> 3-4 blocks/CU) + named-register prefetch of the
// next K-tile (straight-line, no lambdas/arrays -> no scratch) so HBM/L2
// latency drains under the MFMA phase.
#define STAGE_A(v, l)                                                          \
  {                                                                            \
    _Float16 h0 = (_Float16)(v).x, h1 = (_Float16)(v).y,                       \
             h2 = (_Float16)(v).z, h3 = (_Float16)(v).w;                       \
    f16x4 hi4 = {h0, h1, h2, h3};                                              \
    f16x4 lo4 = {(_Float16)((v).x - (float)h0), (_Float16)((v).y - (float)h1), \
                 (_Float16)((v).z - (float)h2), (_Float16)((v).w - (float)h3)};\
    *(f16x4*)&sAh[((l) * 32 + ar) * BST + akk] = hi4;                          \
    *(f16x4*)&sAl[((l) * 32 + ar) * BST + akk] = lo4;                          \
  }

__global__ __launch_bounds__(256, 3) void gemm1_k(const float* __restrict__ A,
                                                  const __half* __restrict__ Bth,
                                                  const __half* __restrict__ Btl,
                                                  const float* __restrict__ dis,
                                                  __half* __restrict__ hs, int N) {
  __shared__ _Float16 smem[4 * 128 * BST];   // Ah | Al | Bh | Bl = 40960 B
  _Float16* sAh = smem;
  _Float16* sAl = smem + 128 * BST;
  _Float16* sBh = smem + 2 * 128 * BST;
  _Float16* sBl = smem + 3 * 128 * BST;
  const int tid = threadIdx.x;
  const int wave = tid >> 6, lane = tid & 63;
  const int lr = lane & 15, quad = lane >> 4;
  const int m0 = blockIdx.x * 128;
  const int mbase = (wave >> 1) * 64;   // wave owns 64x64 of the 128x128 tile
  const int nbase = (wave & 1) * 64;

  const int ar  = tid >> 3;             // A row within 32-row group
  const int akk = (tid & 7) << 2;       // A fp32 col within 32-k tile
  const int br0 = tid >> 2;             // B staging rows (two 16B chunks/thread)
  const int br1 = (256 + tid) >> 2;
  const int bcc = (tid & 3) << 3;       // B f16 col within 32-k tile

  const int g0 = m0 + ar,      g1 = m0 + 32 + ar;
  const int g2 = m0 + 64 + ar, g3 = m0 + 96 + ar;
  const float* a0p = A + (size_t)g0 * DIN + akk;
  const float* a1p = A + (size_t)g1 * DIN + akk;
  const float* a2p = A + (size_t)g2 * DIN + akk;
  const float* a3p = A + (size_t)g3 * DIN + akk;
  const __half* bh0p = Bth + (size_t)br0 * DIN + bcc;
  const __half* bh1p = Bth + (size_t)br1 * DIN + bcc;
  const __half* bl0p = Btl + (size_t)br0 * DIN + bcc;
  const __half* bl1p = Btl + (size_t)br1 * DIN + bcc;

  f32x4 acc[4][4];
  #pragma unroll
  for (int mt = 0; mt < 4; ++mt)
    #pragma unroll
    for (int nt = 0; nt < 4; ++nt) acc[mt][nt] = (f32x4){0.f, 0.f, 0.f, 0.f};

  const float4 z4 = make_float4(0.f, 0.f, 0.f, 0.f);
  // prologue prefetch: K-tile 0
  float4 pa0 = (g0 < N) ? *(const float4*)a0p : z4;
  float4 pa1 = (g1 < N) ? *(const float4*)a1p : z4;
  float4 pa2 = (g2 < N) ? *(const float4*)a2p : z4;
  float4 pa3 = (g3 < N) ? *(const float4*)a3p : z4;
  uint4 pbh0 = *(const uint4*)bh0p;
  uint4 pbh1 = *(const uint4*)bh1p;
  uint4 pbl0 = *(const uint4*)bl0p;
  uint4 pbl1 = *(const uint4*)bl1p;

  for (int k0 = 0; k0 < DIN; k0 += 32) {
    // ---- stage phase: consume prefetch regs (cvt + LDS write), no loads ----
    STAGE_A(pa0, 0);
    STAGE_A(pa1, 1);
    STAGE_A(pa2, 2);
    STAGE_A(pa3, 3);
    *(uint4*)&sBh[br0 * BST + bcc] = pbh0;
    *(uint4*)&sBh[br1 * BST + bcc] = pbh1;
    *(uint4*)&sBl[br0 * BST + bcc] = pbl0;
    *(uint4*)&sBl[br1 * BST + bcc] = pbl1;
    __syncthreads();
    // ---- issue next K-tile loads: drain under the MFMA phase below ----
    if (k0 + 32 < DIN) {
      const int k1 = k0 + 32;
      pa0 = (g0 < N) ? *(const float4*)(a0p + k1) : z4;
      pa1 = (g1 < N) ? *(const float4*)(a1p + k1) : z4;
      pa2 = (g2 < N) ? *(const float4*)(a2p + k1) : z4;
      pa3 = (g3 < N) ? *(const float4*)(a3p + k1) : z4;
      pbh0 = *(const uint4*)(bh0p + k1);
      pbh1 = *(const uint4*)(bh1p + k1);
      pbl0 = *(const uint4*)(bl0p + k1);
      pbl1 = *(const uint4*)(bl1p + k1);
    }
    // ---- MFMA phase ----
    const int ko = quad * 8;
    f16x8 ah[4], al[4];
    #pragma unroll
    for (int mt = 0; mt < 4; ++mt) {
      int r = mbase + mt * 16 + lr;
      ah[mt] = *(const f16x8*)&sAh[r * BST + ko];
      al[mt] = *(const f16x8*)&sAl[r * BST + ko];
    }
    #pragma unroll
    for (int nt = 0; nt < 4; ++nt) {
      int c = nbase + nt * 16 + lr;
      f16x8 bh = *(const f16x8*)&sBh[c * BST + ko];
      f16x8 bl = *(const f16x8*)&sBl[c * BST + ko];
      #pragma unroll
      for (int mt = 0; mt < 4; ++mt)
        acc[mt][nt] = __builtin_amdgcn_mfma_f32_16x16x32_f16(al[mt], bh, acc[mt][nt], 0, 0, 0);
      #pragma unroll
      for (int mt = 0; mt < 4; ++mt)
        acc[mt][nt] = __builtin_amdgcn_mfma_f32_16x16x32_f16(ah[mt], bl, acc[mt][nt], 0, 0, 0);
      #pragma unroll
      for (int mt = 0; mt < 4; ++mt)
        acc[mt][nt] = __builtin_amdgcn_mfma_f32_16x16x32_f16(ah[mt], bh, acc[mt][nt], 0, 0, 0);
    }
    __syncthreads();
  }
  // epilogue: scale by dis (direct L1/L2 loads), fp16 round via LDS [128][136]
  #pragma unroll
  for (int mt = 0; mt < 4; ++mt) {
    #pragma unroll
    for (int r = 0; r < 4; ++r) {
      int row = mbase + mt * 16 + quad * 4 + r;
      int gr = m0 + row;
      float dv = dis[gr < N ? gr : (N - 1)];
      #pragma unroll
      for (int nt = 0; nt < 4; ++nt) {
        int col = nbase + nt * 16 + lr;
        smem[row * 136 + col] = (_Float16)(acc[mt][nt][r] * dv);
      }
    }
  }
  __syncthreads();
  #pragma unroll
  for (int l = 0; l < 8; ++l) {
    int idx = l * 256 + tid;
    int row = idx >> 4;
    int c = (idx & 15) << 3;
    int gr = m0 + row;
    if (gr < N)
      *(uint4*)(hs + (size_t)gr * DHID + c) = *(uint4*)&smem[row * 136 + c];
  }
}

// ---------- fused agg1, unroll-8 gather for memory-level parallelism ----------
__global__ __launch_bounds__(256) void agg1_k(const __half* __restrict__ hs,
                                              const float* __restrict__ dis,
                                              const int* __restrict__ offs,
                                              const int* __restrict__ csr,
                                              const float* __restrict__ W2,
                                              const float* __restrict__ b1,
                                              float* __restrict__ gs, int N) {
  const int wid = threadIdx.x >> 6;
  const int lane = threadIdx.x & 63;
  const int i = blockIdx.x * 4 + wid;
  if (i >= N) return;
  const int f = lane * 2;
  const __half* hp = hs + f;   // lane-fixed column base
  float ax = 0.f, ay = 0.f;
  const int beg = offs[i], end = offs[i + 1];
  for (int base = beg; base < end; base += 64) {
    int sj = 0;
    if (base + lane < end) sj = csr[base + lane];  // coalesced edge-id load
    const int n = min(64, end - base);
    int t = 0;
    for (; t + 8 <= n; t += 8) {   // 8 independent gathers in flight
      int s0 = __shfl(sj, t + 0, 64), s1 = __shfl(sj, t + 1, 64);
      int s2 = __shfl(sj, t + 2, 64), s3 = __shfl(sj, t + 3, 64);
      int s4 = __shfl(sj, t + 4, 64), s5 = __shfl(sj, t + 5, 64);
      int s6 = __shfl(sj, t + 6, 64), s7 = __shfl(sj, t + 7, 64);
      __half2 h0 = *(const __half2*)(hp + (size_t)s0 * DHID);
      __half2 h1 = *(const __half2*)(hp + (size_t)s1 * DHID);
      __half2 h2 = *(const __half2*)(hp + (size_t)s2 * DHID);
      __half2 h3 = *(const __half2*)(hp + (size_t)s3 * DHID);
      __half2 h4 = *(const __half2*)(hp + (size_t)s4 * DHID);
      __half2 h5 = *(const __half2*)(hp + (size_t)s5 * DHID);
      __half2 h6 = *(const __half2*)(hp + (size_t)s6 * DHID);
      __half2 h7 = *(const __half2*)(hp + (size_t)s7 * DHID);
      float2 f0 = __half22float2(h0), f1 = __half22float2(h1);
      float2 f2 = __half22float2(h2), f3 = __half22float2(h3);
      float2 f4 = __half22float2(h4), f5 = __half22float2(h5);
      float2 f6 = __half22float2(h6), f7 = __half22float2(h7);
      ax += ((f0.x + f1.x) + (f2.x + f3.x)) + ((f4.x + f5.x) + (f6.x + f7.x));
      ay += ((f0.y + f1.y) + (f2.y + f3.y)) + ((f4.y + f5.y) + (f6.y + f7.y));
    }
    for (; t < n; ++t) {
      int s = __shfl(sj, t, 64);
      float2 hf = __half22float2(*(const __half2*)(hp + (size_t)s * DHID));
      ax += hf.x;
      ay += hf.y;
    }
  }
  {  // self-loop
    float2 hf = __half22float2(*(const __half2*)(hp + (size_t)i * DHID));
    ax += hf.x;
    ay += hf.y;
  }
  const float di = dis[i];
  float v0 = fmaxf(fmaf(ax, di, b1[f]), 0.f);
  float v1 = fmaxf(fmaf(ay, di, b1[f + 1]), 0.f);
  float p0 = fmaf(v0, W2[f * 4 + 0], v1 * W2[f * 4 + 4]);
  float p1 = fmaf(v0, W2[f * 4 + 1], v1 * W2[f * 4 + 5]);
  float p2 = fmaf(v0, W2[f * 4 + 2], v1 * W2[f * 4 + 6]);
  float p3 = fmaf(v0, W2[f * 4 + 3], v1 * W2[f * 4 + 7]);
  #pragma unroll
  for (int o = 32; o > 0; o >>= 1) {
    p0 += __shfl_xor(p0, o, 64);
    p1 += __shfl_xor(p1, o, 64);
    p2 += __shfl_xor(p2, o, 64);
    p3 += __shfl_xor(p3, o, 64);
  }
  if (lane == 0)
    *(float4*)(gs + (size_t)i * DOUT) = make_float4(p0 * di, p1 * di, p2 * di, p3 * di);
}

// ---------- layer-2: out = dis_i*(sum gs[s] + gs[i]) + b2, unroll-4 ----------
__global__ __launch_bounds__(256) void agg2_k(const float* __restrict__ gs,
                                              const float* __restrict__ dis,
                                              const int* __restrict__ offs,
                                              const int* __restrict__ csr,
                                              const float* __restrict__ b2,
                                              float* __restrict__ out, int N) {
  int i = blockIdx.x * 256 + threadIdx.x;
  if (i >= N) return;
  float a0 = 0.f, a1 = 0.f, a2 = 0.f, a3 = 0.f;
  const int beg = offs[i], end = offs[i + 1];
  int j = beg;
  for (; j + 4 <= end; j += 4) {
    int s0 = csr[j], s1 = csr[j + 1], s2 = csr[j + 2], s3 = csr[j + 3];
    float4 g0 = *(const float4*)(gs + (size_t)s0 * DOUT);
    float4 g1 = *(const float4*)(gs + (size_t)s1 * DOUT);
    float4 g2 = *(const float4*)(gs + (size_t)s2 * DOUT);
    float4 g3 = *(const float4*)(gs + (size_t)s3 * DOUT);
    a0 += (g0.x + g1.x) + (g2.x + g3.x);
    a1 += (g0.y + g1.y) + (g2.y + g3.y);
    a2 += (g0.z + g1.z) + (g2.z + g3.z);
    a3 += (g0.w + g1.w) + (g2.w + g3.w);
  }
  for (; j < end; ++j) {
    int s = csr[j];
    float4 gv = *(const float4*)(gs + (size_t)s * DOUT);
    a0 += gv.x; a1 += gv.y; a2 += gv.z; a3 += gv.w;
  }
  const float di = dis[i];
  float4 gi = *(const float4*)(gs + (size_t)i * DOUT);
  float4 o4;
  o4.x = fmaf(a0 + gi.x, di, b2[0]);
  o4.y = fmaf(a1 + gi.y, di, b2[1]);
  o4.z = fmaf(a2 + gi.z, di, b2[2]);
  o4.w = fmaf(a3 + gi.w, di, b2[3]);
  *(float4*)(out + (size_t)i * DOUT) = o4;
}

extern "C" void kernel_launch(void* const* d_in, const int* in_sizes, int n_in,
                              void* d_out, int out_size, void* d_ws, size_t ws_size,
                              hipStream_t stream) {
  const float* x  = (const float*)d_in[0];
  const int*   raw = (const int*)d_in[1];
  const float* W1 = (const float*)d_in[2];
  const float* b1 = (const float*)d_in[3];
  const float* W2 = (const float*)d_in[4];
  const float* b2 = (const float*)d_in[5];
  float* out = (float*)d_out;

  const int N = in_sizes[0] / DIN;   // 100000
  const int E = in_sizes[1] / 2;     // 3200000

  char* ws = (char*)d_ws;
  size_t off = 0;
  auto carve = [&](size_t bytes) -> char* {
    char* p = ws + off;
    off = (off + bytes + 255) & ~(size_t)255;
    return p;
  };
  float*    dis  = (float*)carve((size_t)N * 4);
  int*      offs = (int*)carve((size_t)(N + 1) * 4);
  int*      csr  = (int*)carve((size_t)E * 4);
  unsigned* pairs= (unsigned*)carve((size_t)E * 4);
  int*      boffs= (int*)carve(513 * 4);
  int*      bcur = (int*)carve(512 * 4);
  int*      gbcnt= (int*)carve(512 * 4);
  int*      flag = (int*)carve(256);
  __half*   Wth  = (__half*)carve((size_t)DIN * DHID * 2);
  __half*   Wtl  = (__half*)carve((size_t)DIN * DHID * 2);
  __half*   hs   = (__half*)carve((size_t)N * DHID * 2);
  float*    gs   = (float*)carve((size_t)N * DOUT * 4);
  (void)ws_size; (void)n_in; (void)out_size;

  const int gN = (N + 255) / 256;
  const int nbkt = (N + (1 << BSH) - 1) >> BSH;   // 391
  const int gA = (E + PA_CHUNK - 1) / PA_CHUNK;   // 391

  detect_i64_k<<<1, 64, 0, stream>>>(raw, flag);
  hipMemsetAsync(gbcnt, 0, 512 * 4, stream);
  bcount_k<<<gA, 256, 0, stream>>>(raw, flag, gbcnt, E);
  bscan_k<<<1, 512, 0, stream>>>(gbcnt, boffs, bcur, offs, nbkt, N, E);
  binA_k<<<gA, 256, 0, stream>>>(raw, flag, bcur, pairs, E);
  binB_k<<<nbkt, 256, 0, stream>>>(pairs, boffs, csr, offs, dis, N);
  wsplit_k<<<(DIN * DHID + 255) / 256, 256, 0, stream>>>(W1, Wth, Wtl);
  gemm1_k<<<(N + 127) / 128, 256, 0, stream>>>(x, Wth, Wtl, dis, hs, N);
  agg1_k<<<(N + 3) / 4, 256, 0, stream>>>(hs, dis, offs, csr, W2, b1, gs, N);
  agg2_k<<<gN, 256, 0, stream>>>(gs, dis, offs, csr, b2, out, N);
}